// Round 1
// baseline (149.811 us; speedup 1.0000x reference)
//
#include <hip/hip_runtime.h>
#include <hip/hip_bf16.h>

#define B_    64
#define S_    513
#define T_    512
#define H_    1024
#define OUT_  128

#define TILE_T 64
#define TILE_K 32

// ---------------------------------------------------------------------------
// Kernel 1: per-batch segment info. segments are contiguous runs; for each
// segment id s: start position and count. cnt==0 for s >= nseg.
// one block per batch, 512 threads (one per position).
// ---------------------------------------------------------------------------
__global__ __launch_bounds__(T_) void seg_info_kernel(
    const int* __restrict__ seg, int* __restrict__ seg_start,
    int* __restrict__ seg_cnt)
{
    int b = blockIdx.x;
    int t = threadIdx.x;
    __shared__ int s_start[T_];
    __shared__ int s_cnt[T_];
    s_start[t] = T_;
    s_cnt[t]   = 0;
    __syncthreads();
    int sid = seg[b * T_ + t];
    atomicMin(&s_start[sid], t);
    atomicAdd(&s_cnt[sid], 1);
    __syncthreads();
    seg_start[b * T_ + t] = s_start[t];
    seg_cnt[b * T_ + t]   = s_cnt[t];
}

// ---------------------------------------------------------------------------
// Kernel 2: logits = x @ W + bias, x = hidden_states[:,1:,:]  (fp32 baseline)
// block tile: 64 T-rows x 128 OUT-cols, 256 threads, 4x8 register blocking.
// grid: B * (T/64) = 512 blocks.
// ---------------------------------------------------------------------------
__global__ __launch_bounds__(256) void gemm_kernel(
    const float* __restrict__ hs, const float* __restrict__ W,
    const float* __restrict__ bias, float* __restrict__ logits)
{
    int blk = blockIdx.x;
    int b   = blk >> 3;            // / (T_/TILE_T) = /8
    int t0  = (blk & 7) * TILE_T;
    int tid = threadIdx.x;
    int tx  = tid & 15;            // 16 col-groups of 8
    int ty  = tid >> 4;            // 16 row-groups of 4

    __shared__ float xs[TILE_T][TILE_K + 1];   // 64 x 33
    __shared__ float wsm[TILE_K][OUT_ + 4];    // 32 x 132

    float acc[4][8];
#pragma unroll
    for (int i = 0; i < 4; ++i)
#pragma unroll
        for (int j = 0; j < 8; ++j) acc[i][j] = 0.f;

    const float* xbase = hs + ((size_t)b * S_ + 1 + t0) * H_;

    for (int kk = 0; kk < H_; kk += TILE_K) {
        // stage x tile: 64 rows x 32 cols (float4, coalesced)
#pragma unroll
        for (int p = 0; p < 2; ++p) {
            int li  = tid + p * 256;     // 0..511
            int row = li >> 3;
            int c4  = li & 7;
            float4 v = *reinterpret_cast<const float4*>(
                xbase + (size_t)row * H_ + kk + c4 * 4);
            xs[row][c4 * 4 + 0] = v.x;
            xs[row][c4 * 4 + 1] = v.y;
            xs[row][c4 * 4 + 2] = v.z;
            xs[row][c4 * 4 + 3] = v.w;
        }
        // stage W tile: 32 rows x 128 cols (float4, coalesced)
#pragma unroll
        for (int p = 0; p < 4; ++p) {
            int li  = tid + p * 256;     // 0..1023
            int row = li >> 5;
            int c4  = li & 31;
            float4 v = *reinterpret_cast<const float4*>(
                W + (size_t)(kk + row) * OUT_ + c4 * 4);
            wsm[row][c4 * 4 + 0] = v.x;
            wsm[row][c4 * 4 + 1] = v.y;
            wsm[row][c4 * 4 + 2] = v.z;
            wsm[row][c4 * 4 + 3] = v.w;
        }
        __syncthreads();

#pragma unroll
        for (int k = 0; k < TILE_K; ++k) {
            float a0 = xs[ty * 4 + 0][k];
            float a1 = xs[ty * 4 + 1][k];
            float a2 = xs[ty * 4 + 2][k];
            float a3 = xs[ty * 4 + 3][k];
            float wv[8];
#pragma unroll
            for (int j = 0; j < 8; ++j) wv[j] = wsm[k][tx * 8 + j];
#pragma unroll
            for (int j = 0; j < 8; ++j) {
                acc[0][j] += a0 * wv[j];
                acc[1][j] += a1 * wv[j];
                acc[2][j] += a2 * wv[j];
                acc[3][j] += a3 * wv[j];
            }
        }
        __syncthreads();
    }

    // epilogue: add bias, store logits[b][t][o]
#pragma unroll
    for (int i = 0; i < 4; ++i) {
        int t = t0 + ty * 4 + i;
        float* dst = logits + ((size_t)b * T_ + t) * OUT_ + tx * 8;
#pragma unroll
        for (int j = 0; j < 8; ++j) dst[j] = acc[i][j] + bias[tx * 8 + j];
    }
}

// ---------------------------------------------------------------------------
// Kernel 3: merge — out[b][o][s] = mean over run of logits[b][t][o], 0 if empty
// block: one b, 32-segment tile, all 128 outs. 256 threads.
// phase 1 reads logits coalesced along o; phase 2 writes out coalesced along s
// via an LDS transpose tile.
// grid: B * (T/32) = 1024 blocks.
// ---------------------------------------------------------------------------
__global__ __launch_bounds__(256) void merge_kernel(
    const float* __restrict__ logits, const int* __restrict__ seg_start,
    const int* __restrict__ seg_cnt, float* __restrict__ out)
{
    int blk = blockIdx.x;
    int b   = blk >> 4;            // / (T_/32)
    int s0  = (blk & 15) * 32;
    int tid = threadIdx.x;

    __shared__ float tile[OUT_][33];   // [o][s_local], padded

    // phase 1: compute per-segment means (consecutive tid -> consecutive o)
#pragma unroll
    for (int it = 0; it < 16; ++it) {
        int idx = tid + it * 256;      // 0..4095
        int sl  = idx >> 7;            // 0..31
        int o   = idx & 127;
        int s   = s0 + sl;
        int cnt = seg_cnt[b * T_ + s];
        float v = 0.f;
        if (cnt > 0) {
            int st = seg_start[b * T_ + s];
            float sum = 0.f;
            for (int i = 0; i < cnt; ++i)
                sum += logits[((size_t)b * T_ + st + i) * OUT_ + o];
            v = sum / (float)cnt;
        }
        tile[o][sl] = v;
    }
    __syncthreads();

    // phase 2: write out coalesced along s
#pragma unroll
    for (int p = 0; p < 16; ++p) {
        int o  = (tid >> 5) + p * 8;
        int sl = tid & 31;
        out[((size_t)b * OUT_ + o) * T_ + s0 + sl] = tile[o][sl];
    }
}

// ---------------------------------------------------------------------------
extern "C" void kernel_launch(void* const* d_in, const int* in_sizes, int n_in,
                              void* d_out, int out_size, void* d_ws, size_t ws_size,
                              hipStream_t stream) {
    const float* hs   = (const float*)d_in[0];   // (B, S, H)
    const float* W    = (const float*)d_in[1];   // (H, OUT)
    const float* bias = (const float*)d_in[2];   // (OUT,)
    const int*   seg  = (const int*)d_in[3];     // (B, T)
    float* out = (float*)d_out;                  // (B, OUT, T)

    // workspace layout: logits (B*T*OUT f32) | seg_start (B*T i32) | seg_cnt
    float* logits    = (float*)d_ws;
    int*   seg_start = (int*)((char*)d_ws + (size_t)B_ * T_ * OUT_ * sizeof(float));
    int*   seg_cnt   = seg_start + (size_t)B_ * T_;

    seg_info_kernel<<<B_, T_, 0, stream>>>(seg, seg_start, seg_cnt);
    gemm_kernel<<<B_ * (T_ / TILE_T), 256, 0, stream>>>(hs, W, bias, logits);
    merge_kernel<<<B_ * (T_ / 32), 256, 0, stream>>>(logits, seg_start, seg_cnt, out);
}

// Round 2
// 56.753 us; speedup vs baseline: 2.6397x; 2.6397x over previous
//
#include <hip/hip_runtime.h>
#include <hip/hip_bf16.h>

#define B_    64
#define S_    513
#define T_    512
#define H_    1024
#define OUT_  128

#define BM 64
#define BN 128
#define BK 32
#define NKT (H_ / BK)   // 32

typedef __attribute__((ext_vector_type(8))) short short8_t;
typedef __attribute__((ext_vector_type(4))) float f32x4;

__device__ inline ushort f2bf(float f) {
    union { float f; unsigned u; } x; x.f = f;
    unsigned r = x.u + 0x7fffu + ((x.u >> 16) & 1u);   // round-to-nearest-even
    return (ushort)(r >> 16);
}

// ---------------------------------------------------------------------------
// Kernel 0: Wt[o][k] = bf16(W[k][o])  — 64x64 LDS tile transpose
// grid (H/64, OUT/64) = (16, 2), 256 threads
// ---------------------------------------------------------------------------
__global__ __launch_bounds__(256) void wt_kernel(
    const float* __restrict__ W, ushort* __restrict__ Wt)
{
    __shared__ ushort tile[64][65];
    int k0 = blockIdx.x * 64, o0 = blockIdx.y * 64;
    int tid = threadIdx.x;
#pragma unroll
    for (int p = 0; p < 16; ++p) {
        int idx = tid + p * 256;
        int r = idx >> 6, c = idx & 63;
        tile[r][c] = f2bf(W[(size_t)(k0 + r) * OUT_ + o0 + c]);
    }
    __syncthreads();
#pragma unroll
    for (int p = 0; p < 16; ++p) {
        int idx = tid + p * 256;
        int c = idx >> 6, r = idx & 63;
        Wt[(size_t)(o0 + c) * H_ + k0 + r] = tile[r][c];
    }
}

// ---------------------------------------------------------------------------
// Kernel 1: per-batch segment start/count (contiguous runs)
// ---------------------------------------------------------------------------
__global__ __launch_bounds__(T_) void seg_info_kernel(
    const int* __restrict__ seg, int* __restrict__ seg_start,
    int* __restrict__ seg_cnt)
{
    int b = blockIdx.x;
    int t = threadIdx.x;
    __shared__ int s_start[T_];
    __shared__ int s_cnt[T_];
    s_start[t] = T_;
    s_cnt[t]   = 0;
    __syncthreads();
    int sid = seg[b * T_ + t];
    atomicMin(&s_start[sid], t);
    atomicAdd(&s_cnt[sid], 1);
    __syncthreads();
    seg_start[b * T_ + t] = s_start[t];
    seg_cnt[b * T_ + t]   = s_cnt[t];
}

// ---------------------------------------------------------------------------
// Kernel 2: logits = bf16(x) @ bf16(W) + b via MFMA 16x16x32
// tile 64(T) x 128(OUT), BK=32, 256 threads = 4 waves (2x2), wave tile 32x64.
// LDS XOR-swizzle (blk ^= (row>>1)&3) -> conflict-free b128 write & read.
// Double-buffered, loads issued before compute, 1 barrier/iter.
// grid: B * (T/64) = 512 blocks.
// ---------------------------------------------------------------------------
__global__ __launch_bounds__(256) void gemm_kernel(
    const float* __restrict__ hs, const ushort* __restrict__ Wt,
    const float* __restrict__ bias, float* __restrict__ logits)
{
    __shared__ __align__(16) ushort As[2][BM * BK];
    __shared__ __align__(16) ushort Bs[2][BN * BK];

    int blk = blockIdx.x;
    int b   = blk >> 3;
    int t0  = (blk & 7) * BM;
    int tid = threadIdx.x;
    int lane = tid & 63;
    int wv = tid >> 6;
    int wm = wv & 1, wn = wv >> 1;
    int l15 = lane & 15, ksl = lane >> 4;

    // staging coords: 16B chunk per thread for A, two for B
    int rowA = tid >> 2;          // 0..63
    int cblk = tid & 3;           // 0..3 (8-bf16 chunk within BK)
    int rowB1 = rowA + 64;

    const float*  aptr  = hs + ((size_t)(b * S_ + 1 + t0) + rowA) * H_ + cblk * 8;
    const ushort* bptr0 = Wt + (size_t)rowA  * H_ + cblk * 8;
    const ushort* bptr1 = Wt + (size_t)rowB1 * H_ + cblk * 8;

    // swizzled LDS element offsets
    auto swz = [](int row, int blkc) {
        return row * BK + ((blkc ^ ((row >> 1) & 3)) << 3);
    };
    int wAo  = swz(rowA, cblk);
    int wB0o = swz(rowA, cblk);
    int wB1o = swz(rowB1, cblk);

    int rAo[2], rBo[4];
#pragma unroll
    for (int fm = 0; fm < 2; ++fm) {
        int row = wm * 32 + fm * 16 + l15;
        rAo[fm] = swz(row, ksl);
    }
#pragma unroll
    for (int fn = 0; fn < 4; ++fn) {
        int row = wn * 64 + fn * 16 + l15;
        rBo[fn] = swz(row, ksl);
    }

    f32x4 acc[2][4];
#pragma unroll
    for (int fm = 0; fm < 2; ++fm)
#pragma unroll
        for (int fn = 0; fn < 4; ++fn) acc[fm][fn] = (f32x4){0.f, 0.f, 0.f, 0.f};

    float4 ra0, ra1;
    int4 rb0, rb1;

    auto loadT = [&](int kt) {
        const float* ap = aptr + kt * BK;
        ra0 = *reinterpret_cast<const float4*>(ap);
        ra1 = *reinterpret_cast<const float4*>(ap + 4);
        rb0 = *reinterpret_cast<const int4*>(bptr0 + kt * BK);
        rb1 = *reinterpret_cast<const int4*>(bptr1 + kt * BK);
    };
    auto writeT = [&](int nb) {
        union { ushort u[8]; int4 i; } pa;
        pa.u[0] = f2bf(ra0.x); pa.u[1] = f2bf(ra0.y);
        pa.u[2] = f2bf(ra0.z); pa.u[3] = f2bf(ra0.w);
        pa.u[4] = f2bf(ra1.x); pa.u[5] = f2bf(ra1.y);
        pa.u[6] = f2bf(ra1.z); pa.u[7] = f2bf(ra1.w);
        *reinterpret_cast<int4*>(&As[nb][wAo])  = pa.i;
        *reinterpret_cast<int4*>(&Bs[nb][wB0o]) = rb0;
        *reinterpret_cast<int4*>(&Bs[nb][wB1o]) = rb1;
    };
    auto computeT = [&](int cb) {
        short8_t af[2], bf[4];
#pragma unroll
        for (int fm = 0; fm < 2; ++fm)
            af[fm] = *reinterpret_cast<const short8_t*>(&As[cb][rAo[fm]]);
#pragma unroll
        for (int fn = 0; fn < 4; ++fn)
            bf[fn] = *reinterpret_cast<const short8_t*>(&Bs[cb][rBo[fn]]);
#pragma unroll
        for (int fm = 0; fm < 2; ++fm)
#pragma unroll
            for (int fn = 0; fn < 4; ++fn)
                acc[fm][fn] = __builtin_amdgcn_mfma_f32_16x16x32_bf16(
                    af[fm], bf[fn], acc[fm][fn], 0, 0, 0);
    };

    loadT(0);
    writeT(0);
    __syncthreads();

    for (int kt = 0; kt < NKT; ++kt) {
        int cb = kt & 1;
        if (kt + 1 < NKT) loadT(kt + 1);
        computeT(cb);
        if (kt + 1 < NKT) writeT(cb ^ 1);
        __syncthreads();
    }

    // epilogue: bias + store fp32 logits
#pragma unroll
    for (int fn = 0; fn < 4; ++fn) {
        int o = wn * 64 + fn * 16 + l15;
        float bv = bias[o];
#pragma unroll
        for (int fm = 0; fm < 2; ++fm) {
#pragma unroll
            for (int r = 0; r < 4; ++r) {
                int t = t0 + wm * 32 + fm * 16 + ksl * 4 + r;
                logits[((size_t)b * T_ + t) * OUT_ + o] = acc[fm][fn][r] + bv;
            }
        }
    }
}

// ---------------------------------------------------------------------------
// Kernel 3: merge — out[b][o][s] = mean over run of logits[b][t][o]
// ---------------------------------------------------------------------------
__global__ __launch_bounds__(256) void merge_kernel(
    const float* __restrict__ logits, const int* __restrict__ seg_start,
    const int* __restrict__ seg_cnt, float* __restrict__ out)
{
    int blk = blockIdx.x;
    int b   = blk >> 4;
    int s0  = (blk & 15) * 32;
    int tid = threadIdx.x;

    __shared__ float tile[OUT_][33];

#pragma unroll
    for (int it = 0; it < 16; ++it) {
        int idx = tid + it * 256;
        int sl  = idx >> 7;
        int o   = idx & 127;
        int s   = s0 + sl;
        int cnt = seg_cnt[b * T_ + s];
        float v = 0.f;
        if (cnt > 0) {
            int st = seg_start[b * T_ + s];
            float sum = 0.f;
            for (int i = 0; i < cnt; ++i)
                sum += logits[((size_t)b * T_ + st + i) * OUT_ + o];
            v = sum / (float)cnt;
        }
        tile[o][sl] = v;
    }
    __syncthreads();

#pragma unroll
    for (int p = 0; p < 16; ++p) {
        int o  = (tid >> 5) + p * 8;
        int sl = tid & 31;
        out[((size_t)b * OUT_ + o) * T_ + s0 + sl] = tile[o][sl];
    }
}

// ---------------------------------------------------------------------------
extern "C" void kernel_launch(void* const* d_in, const int* in_sizes, int n_in,
                              void* d_out, int out_size, void* d_ws, size_t ws_size,
                              hipStream_t stream) {
    const float* hs   = (const float*)d_in[0];   // (B, S, H)
    const float* W    = (const float*)d_in[1];   // (H, OUT)
    const float* bias = (const float*)d_in[2];   // (OUT,)
    const int*   seg  = (const int*)d_in[3];     // (B, T)
    float* out = (float*)d_out;                  // (B, OUT, T)

    // ws layout: logits f32 | seg_start i32 | seg_cnt i32 | Wt bf16
    float* logits    = (float*)d_ws;
    int*   seg_start = (int*)((char*)d_ws + (size_t)B_ * T_ * OUT_ * sizeof(float));
    int*   seg_cnt   = seg_start + (size_t)B_ * T_;
    ushort* Wt       = (ushort*)(seg_cnt + (size_t)B_ * T_);

    wt_kernel<<<dim3(H_ / 64, OUT_ / 64), 256, 0, stream>>>(W, Wt);
    seg_info_kernel<<<B_, T_, 0, stream>>>(seg, seg_start, seg_cnt);
    gemm_kernel<<<B_ * (T_ / BM), 256, 0, stream>>>(hs, Wt, bias, logits);
    merge_kernel<<<B_ * (T_ / 32), 256, 0, stream>>>(logits, seg_start, seg_cnt, out);
}